// Round 1
// baseline (436.556 us; speedup 1.0000x reference)
//
#include <hip/hip_runtime.h>

// IntSoftmax (I-BERT) on (1,16,2048,2048) fp32. One 256-thread block per row
// of 2048; row held in registers (8 floats/thread). Bit-exact float32
// replication of the numpy reference: __f*_rn intrinsics forbid FMA
// contraction; rintf == np.round (RNE); ldexpf gives exact 2^(30-q).
// QuantAct global max is analytic (attained at every row's argmax where
// x_int==0 exactly), so no cross-block reduction is needed.

constexpr int COLS    = 2048;
constexpr int THREADS = 256;

__global__ __launch_bounds__(THREADS)
void IntSoftmax_43774306680979_kernel(const float* __restrict__ x,
                                      const float* __restrict__ sfp,
                                      float* __restrict__ out) {
    const int row = blockIdx.x;
    const int tid = threadIdx.x;
    const float sf = sfp[0];

    // ---- scalar constants, exact float32 replication of reference ----
    const float x0_int = floorf(__fdiv_rn(-0.6931f, sf));                       // floor(X0/sf)
    const float b_int  = floorf(__fdiv_rn((float)(0.96963238 / 0.35815147), sf));
    const float c_int  = floorf(__fdiv_rn((float)(1.0 / 0.35815147),
                                          __fmul_rn(sf, sf)));
    float exp_sf = __fmul_rn(__fmul_rn(0.35815147f, sf), sf);                   // COEF0*sf*sf
    exp_sf = __fdiv_rn(exp_sf, 1073741824.0f);                                  // / 2^30
    const float clampv = __fmul_rn(30.0f, x0_int);                              // CONST*x0_int
    // analytic global max of x_real: exp_int_max = floor(c_int * 2^30)
    const float x_max  = __fmul_rn(floorf(__fmul_rn(c_int, 1073741824.0f)), exp_sf);
    const float act_sf = __fdiv_rn(x_max, 32767.0f);                            // x_max / (2^15-1)

    // ---- load row: 2 coalesced float4 per thread ----
    const float4* __restrict__ xr =
        reinterpret_cast<const float4*>(x + (size_t)row * COLS);
    float4 a = xr[tid];
    float4 b = xr[tid + THREADS];

    float xi[8] = {a.x, a.y, a.z, a.w, b.x, b.y, b.z, b.w};

    // x_int = x / sf; row max
    float m = -INFINITY;
#pragma unroll
    for (int i = 0; i < 8; ++i) {
        xi[i] = __fdiv_rn(xi[i], sf);
        m = fmaxf(m, xi[i]);
    }
#pragma unroll
    for (int off = 32; off > 0; off >>= 1)
        m = fmaxf(m, __shfl_xor(m, off, 64));

    __shared__ float smax[4];
    __shared__ float ssum[4];
    if ((tid & 63) == 0) smax[tid >> 6] = m;
    __syncthreads();
    const float rowmax = fmaxf(fmaxf(smax[0], smax[1]), fmaxf(smax[2], smax[3]));

    // ---- int_exp + int_polynomial + QuantAct(16) per element ----
    float s = 0.0f;
#pragma unroll
    for (int i = 0; i < 8; ++i) {
        float t = __fsub_rn(xi[i], rowmax);          // x_int - max
        t = fmaxf(t, clampv);                        // max(x_int, 30*x0_int)
        float q = floorf(__fdiv_rn(t, x0_int));      // 0 <= q <= 30
        float r = __fsub_rn(t, __fmul_rn(x0_int, q));
        float z = __fadd_rn(__fmul_rn(__fadd_rn(r, b_int), r), c_int);
        float p = ldexpf(1.0f, 30 - (int)q);         // exact 2^(30-q)
        float ei = fmaxf(floorf(__fmul_rn(z, p)), 0.0f);
        float xreal = __fmul_rn(ei, exp_sf);
        float qv = __fdiv_rn(xreal, act_sf);
        float rq = rintf(qv);                        // np.round: half-to-even
        rq = fminf(rq, 32767.0f);
        rq = fmaxf(rq, -32768.0f);
        xi[i] = rq;                                  // keep quantized value
        s = __fadd_rn(s, rq);                        // exact: integers, sum < 2^24
    }

    // ---- row sum (exact integers -> order-independent) ----
#pragma unroll
    for (int off = 32; off > 0; off >>= 1)
        s = __fadd_rn(s, __shfl_xor(s, off, 64));
    if ((tid & 63) == 0) ssum[tid >> 6] = s;
    __syncthreads();
    const float sum = __fadd_rn(__fadd_rn(ssum[0], ssum[1]),
                                __fadd_rn(ssum[2], ssum[3]));
    const float factor = floorf(__fdiv_rn(4294967296.0f, sum));   // floor(2^32/sum)

    // ---- normalize via bit-shift; out = exp_int * 2^-8 ----
    float o[8];
#pragma unroll
    for (int i = 0; i < 8; ++i) {
        float t = __fdiv_rn(__fmul_rn(xi[i], factor), 16777216.0f); // /2^24 exact
        o[i] = __fmul_rn(floorf(t), 0.00390625f);                   // * 1/256
    }
    float4* __restrict__ orow = reinterpret_cast<float4*>(out + (size_t)row * COLS);
    orow[tid]           = make_float4(o[0], o[1], o[2], o[3]);
    orow[tid + THREADS] = make_float4(o[4], o[5], o[6], o[7]);
}

extern "C" void kernel_launch(void* const* d_in, const int* in_sizes, int n_in,
                              void* d_out, int out_size, void* d_ws, size_t ws_size,
                              hipStream_t stream) {
    const float* x   = (const float*)d_in[0];
    const float* sfp = (const float*)d_in[1];
    float* out       = (float*)d_out;
    const int rows = in_sizes[0] / COLS;   // 32768
    IntSoftmax_43774306680979_kernel<<<dim3(rows), dim3(THREADS), 0, stream>>>(
        x, sfp, out);
}

// Round 2
// 435.507 us; speedup vs baseline: 1.0024x; 1.0024x over previous
//
#include <hip/hip_runtime.h>

// IntSoftmax (I-BERT) on (1,16,2048,2048) fp32. One 256-thread block per row
// of 2048; row held in registers (8 floats/thread). Bit-exact float32
// replication of the numpy reference.
//
// Bit-exactness notes (all verified round 1, absmax = 0.0):
//  - __f*_rn intrinsics forbid FMA contraction where numpy rounds twice.
//  - x/sf: when sf is a power of two the division is exact, so multiply by
//    the (exact) reciprocal is bit-identical. Runtime-gated on mantissa bits.
//  - r = t - x0*q: x0,q are integers with |x0*q| < 2^24 -> product exact ->
//    fmaf(-x0, q, t) rounds once on an exact intermediate == two-step result.
//  - 2^(30-q) built from the exponent field (q in [0,30] guaranteed by clamp).
//  - (xi*factor)/2^24 == (xi*factor)*2^-24 exactly (power-of-two scaling).
//  - round-clamps to [-32768,32767] are dead: 0 <= ei <= emax ==>
//    0 <= qv <= 32767*(1+2^-22) ==> rint(qv) in [0, 32767].
//  - t/x0 and xreal/act_sf keep __fdiv_rn: reciprocal-multiply would flip
//    floor/rint on ~1e-6..4e-3 of elements (borderline double-rounding),
//    each a 1-LSB (3.9e-3) output error > 1.0e-3 threshold.
//  - QuantAct global max is analytic (attained at every row's argmax where
//    x_int == 0 exactly) -> no cross-block reduction needed.

constexpr int COLS    = 2048;
constexpr int THREADS = 256;

__global__ __launch_bounds__(THREADS)
void IntSoftmax_43774306680979_kernel(const float* __restrict__ x,
                                      const float* __restrict__ sfp,
                                      float* __restrict__ out) {
    const int row = blockIdx.x;
    const int tid = threadIdx.x;
    const float sf = sfp[0];

    // ---- scalar constants, exact float32 replication of reference ----
    const float x0_int = floorf(__fdiv_rn(-0.6931f, sf));                       // floor(X0/sf)
    const float b_int  = floorf(__fdiv_rn((float)(0.96963238 / 0.35815147), sf));
    const float c_int  = floorf(__fdiv_rn((float)(1.0 / 0.35815147),
                                          __fmul_rn(sf, sf)));
    float exp_sf = __fmul_rn(__fmul_rn(0.35815147f, sf), sf);                   // COEF0*sf*sf
    exp_sf = __fdiv_rn(exp_sf, 1073741824.0f);                                  // / 2^30
    const float clampv = __fmul_rn(30.0f, x0_int);                              // CONST*x0_int
    // analytic global max of x_real: exp_int_max = floor(c_int * 2^30)
    const float x_max  = __fmul_rn(floorf(__fmul_rn(c_int, 1073741824.0f)), exp_sf);
    const float act_sf = __fdiv_rn(x_max, 32767.0f);                            // x_max / (2^15-1)
    const float neg_x0 = -x0_int;

    // power-of-two sf => x/sf is exact => reciprocal-multiply is bit-identical
    const unsigned sfb = __float_as_uint(sf);
    const bool sf_pow2 = ((sfb & 0x007fffffu) == 0u) && ((sfb & 0x7f800000u) != 0u);
    const float inv_sf = __fdiv_rn(1.0f, sf);    // exact when sf_pow2

    // ---- load row: 2 coalesced float4 per thread ----
    const float4* __restrict__ xr =
        reinterpret_cast<const float4*>(x + (size_t)row * COLS);
    float4 a = xr[tid];
    float4 b = xr[tid + THREADS];

    float xi[8] = {a.x, a.y, a.z, a.w, b.x, b.y, b.z, b.w};

    // x_int = x / sf; row max
    float m = -INFINITY;
    if (sf_pow2) {
#pragma unroll
        for (int i = 0; i < 8; ++i) {
            xi[i] = __fmul_rn(xi[i], inv_sf);
            m = fmaxf(m, xi[i]);
        }
    } else {
#pragma unroll
        for (int i = 0; i < 8; ++i) {
            xi[i] = __fdiv_rn(xi[i], sf);
            m = fmaxf(m, xi[i]);
        }
    }
#pragma unroll
    for (int off = 32; off > 0; off >>= 1)
        m = fmaxf(m, __shfl_xor(m, off, 64));

    __shared__ float smax[4];
    __shared__ float ssum[4];
    if ((tid & 63) == 0) smax[tid >> 6] = m;
    __syncthreads();
    const float rowmax = fmaxf(fmaxf(smax[0], smax[1]), fmaxf(smax[2], smax[3]));

    // ---- int_exp + int_polynomial + QuantAct(16) per element ----
    float s = 0.0f;
#pragma unroll
    for (int i = 0; i < 8; ++i) {
        float t = __fsub_rn(xi[i], rowmax);          // x_int - max
        t = fmaxf(t, clampv);                        // max(x_int, 30*x0_int)
        float q = floorf(__fdiv_rn(t, x0_int));      // 0 <= q <= 30
        float r = fmaf(neg_x0, q, t);                // exact product -> bit-exact
        float z = __fadd_rn(__fmul_rn(__fadd_rn(r, b_int), r), c_int);
        int   qi = (int)q;
        float p = __int_as_float((157 - qi) << 23);  // exact 2^(30-q)
        float ei = fmaxf(floorf(__fmul_rn(z, p)), 0.0f);
        float xreal = __fmul_rn(ei, exp_sf);
        float qv = __fdiv_rn(xreal, act_sf);
        float rq = rintf(qv);                        // np.round: half-to-even
        xi[i] = rq;                                  // in [0, 32767], clamps dead
        s = __fadd_rn(s, rq);                        // exact: integers, sum < 2^24
    }

    // ---- row sum (exact integers -> order-independent) ----
#pragma unroll
    for (int off = 32; off > 0; off >>= 1)
        s = __fadd_rn(s, __shfl_xor(s, off, 64));
    if ((tid & 63) == 0) ssum[tid >> 6] = s;
    __syncthreads();
    const float sum = __fadd_rn(__fadd_rn(ssum[0], ssum[1]),
                                __fadd_rn(ssum[2], ssum[3]));
    const float factor = floorf(__fdiv_rn(4294967296.0f, sum));   // floor(2^32/sum)

    // ---- normalize via bit-shift; out = exp_int * 2^-8 ----
    float o[8];
#pragma unroll
    for (int i = 0; i < 8; ++i) {
        float t = __fmul_rn(__fmul_rn(xi[i], factor), 5.9604644775390625e-8f); // *2^-24 exact
        o[i] = __fmul_rn(floorf(t), 0.00390625f);                              // * 1/256
    }
    float4* __restrict__ orow = reinterpret_cast<float4*>(out + (size_t)row * COLS);
    orow[tid]           = make_float4(o[0], o[1], o[2], o[3]);
    orow[tid + THREADS] = make_float4(o[4], o[5], o[6], o[7]);
}

extern "C" void kernel_launch(void* const* d_in, const int* in_sizes, int n_in,
                              void* d_out, int out_size, void* d_ws, size_t ws_size,
                              hipStream_t stream) {
    const float* x   = (const float*)d_in[0];
    const float* sfp = (const float*)d_in[1];
    float* out       = (float*)d_out;
    const int rows = in_sizes[0] / COLS;   // 32768
    IntSoftmax_43774306680979_kernel<<<dim3(rows), dim3(THREADS), 0, stream>>>(
        x, sfp, out);
}

// Round 4
// 416.032 us; speedup vs baseline: 1.0493x; 1.0468x over previous
//
#include <hip/hip_runtime.h>

// IntSoftmax (I-BERT) on (1,16,2048,2048) fp32. ONE WAVE PER ROW (2048 cols,
// 32 elems/lane): zero __syncthreads, zero LDS, row reductions are pure
// 6-step shfl_xor. 8 back-to-back 16B loads per lane maximize outstanding
// memory ops. Non-temporal load/store hints (streaming, no reuse) — must use
// clang native ext_vector_type, HIP_vector_type structs are rejected.
//
// Bit-exactness notes (verified rounds 1-2, absmax = 0.0):
//  - __f*_rn intrinsics forbid FMA contraction where numpy rounds twice.
//  - x/sf: when sf is a power of two the division is exact, so multiply by
//    the (exact) reciprocal is bit-identical. Runtime-gated on mantissa bits.
//  - r = t - x0*q: x0,q are integers with |x0*q| < 2^24 -> product exact ->
//    fmaf(-x0, q, t) rounds once on an exact intermediate == two-step result.
//  - 2^(30-q) built from the exponent field (q in [0,30] guaranteed by clamp).
//  - (xi*factor)/2^24 == (xi*factor)*2^-24 exactly (power-of-two scaling).
//  - round-clamps to [-32768,32767] are dead: rint(qv) provably in [0,32767].
//  - t/x0 and xreal/act_sf keep __fdiv_rn (reciprocal-mul would flip borderline
//    floor/rint decisions -> 1-LSB = 3.9e-3 errors > 1.0e-3 threshold).
//  - Row sums are exact integer sums < 2^24 -> reduction order irrelevant.
//  - QuantAct global max is analytic (attained at every row's argmax where
//    x_int == 0 exactly) -> no cross-block reduction needed.

typedef float f32x4 __attribute__((ext_vector_type(4)));

constexpr int COLS    = 2048;
constexpr int THREADS = 256;            // 4 waves/block, 1 row per wave
constexpr int ROWS_PER_BLOCK = 4;
constexpr int EPL = 32;                 // elements per lane

__global__ __launch_bounds__(THREADS)
void IntSoftmax_43774306680979_kernel(const float* __restrict__ x,
                                      const float* __restrict__ sfp,
                                      float* __restrict__ out) {
    const int lane = threadIdx.x & 63;
    const int wave = threadIdx.x >> 6;
    const size_t row = (size_t)blockIdx.x * ROWS_PER_BLOCK + wave;
    const float sf = sfp[0];

    // ---- scalar constants, exact float32 replication of reference ----
    const float x0_int = floorf(__fdiv_rn(-0.6931f, sf));                       // floor(X0/sf)
    const float b_int  = floorf(__fdiv_rn((float)(0.96963238 / 0.35815147), sf));
    const float c_int  = floorf(__fdiv_rn((float)(1.0 / 0.35815147),
                                          __fmul_rn(sf, sf)));
    float exp_sf = __fmul_rn(__fmul_rn(0.35815147f, sf), sf);                   // COEF0*sf*sf
    exp_sf = __fdiv_rn(exp_sf, 1073741824.0f);                                  // / 2^30
    const float clampv = __fmul_rn(30.0f, x0_int);                              // CONST*x0_int
    // analytic global max of x_real: exp_int_max = floor(c_int * 2^30)
    const float x_max  = __fmul_rn(floorf(__fmul_rn(c_int, 1073741824.0f)), exp_sf);
    const float act_sf = __fdiv_rn(x_max, 32767.0f);                            // x_max / (2^15-1)
    const float neg_x0 = -x0_int;

    // power-of-two sf => x/sf exact => reciprocal-multiply bit-identical
    const unsigned sfb = __float_as_uint(sf);
    const bool sf_pow2 = ((sfb & 0x007fffffu) == 0u) && ((sfb & 0x7f800000u) != 0u);
    const float inv_sf = __fdiv_rn(1.0f, sf);    // exact when sf_pow2

    // ---- load row: 8 back-to-back coalesced 16B loads per lane ----
    const f32x4* __restrict__ xr =
        reinterpret_cast<const f32x4*>(x + row * COLS);
    f32x4 v[8];
#pragma unroll
    for (int k = 0; k < 8; ++k)
        v[k] = __builtin_nontemporal_load(&xr[lane + 64 * k]);

    float xi[EPL];
#pragma unroll
    for (int k = 0; k < 8; ++k) {
        xi[4 * k + 0] = v[k].x; xi[4 * k + 1] = v[k].y;
        xi[4 * k + 2] = v[k].z; xi[4 * k + 3] = v[k].w;
    }

    // x_int = x / sf; row max
    float m = -INFINITY;
    if (sf_pow2) {
#pragma unroll
        for (int i = 0; i < EPL; ++i) {
            xi[i] = __fmul_rn(xi[i], inv_sf);
            m = fmaxf(m, xi[i]);
        }
    } else {
#pragma unroll
        for (int i = 0; i < EPL; ++i) {
            xi[i] = __fdiv_rn(xi[i], sf);
            m = fmaxf(m, xi[i]);
        }
    }
#pragma unroll
    for (int off = 32; off > 0; off >>= 1)
        m = fmaxf(m, __shfl_xor(m, off, 64));
    const float rowmax = m;

    // ---- int_exp + int_polynomial + QuantAct(16) per element ----
    float s = 0.0f;
#pragma unroll
    for (int i = 0; i < EPL; ++i) {
        float t = __fsub_rn(xi[i], rowmax);          // x_int - max
        t = fmaxf(t, clampv);                        // max(x_int, 30*x0_int)
        float q = floorf(__fdiv_rn(t, x0_int));      // 0 <= q <= 30
        float r = fmaf(neg_x0, q, t);                // exact product -> bit-exact
        float z = __fadd_rn(__fmul_rn(__fadd_rn(r, b_int), r), c_int);
        int   qi = (int)q;
        float p = __int_as_float((157 - qi) << 23);  // exact 2^(30-q)
        float ei = fmaxf(floorf(__fmul_rn(z, p)), 0.0f);
        float xreal = __fmul_rn(ei, exp_sf);
        float qv = __fdiv_rn(xreal, act_sf);
        float rq = rintf(qv);                        // np.round: half-to-even
        xi[i] = rq;                                  // in [0, 32767]
        s = __fadd_rn(s, rq);                        // exact integer sum < 2^24
    }

    // ---- row sum: pure wave reduction, exact ----
#pragma unroll
    for (int off = 32; off > 0; off >>= 1)
        s = __fadd_rn(s, __shfl_xor(s, off, 64));
    const float factor = floorf(__fdiv_rn(4294967296.0f, s));   // floor(2^32/sum)

    // ---- normalize via bit-shift; out = exp_int * 2^-8 ----
    f32x4* __restrict__ orow = reinterpret_cast<f32x4*>(out + row * COLS);
#pragma unroll
    for (int k = 0; k < 8; ++k) {
        f32x4 o;
#pragma unroll
        for (int j = 0; j < 4; ++j) {
            float t = __fmul_rn(__fmul_rn(xi[4 * k + j], factor),
                                5.9604644775390625e-8f);        // *2^-24 exact
            o[j] = __fmul_rn(floorf(t), 0.00390625f);           // * 1/256
        }
        __builtin_nontemporal_store(o, &orow[lane + 64 * k]);
    }
}

extern "C" void kernel_launch(void* const* d_in, const int* in_sizes, int n_in,
                              void* d_out, int out_size, void* d_ws, size_t ws_size,
                              hipStream_t stream) {
    const float* x   = (const float*)d_in[0];
    const float* sfp = (const float*)d_in[1];
    float* out       = (float*)d_out;
    const int rows   = in_sizes[0] / COLS;             // 32768
    const int blocks = rows / ROWS_PER_BLOCK;          // 8192
    IntSoftmax_43774306680979_kernel<<<dim3(blocks), dim3(THREADS), 0, stream>>>(
        x, sfp, out);
}